// Round 1
// baseline (478.210 us; speedup 1.0000x reference)
//
#include <hip/hip_runtime.h>

#define DIM 128
#define KCODES 1024
#define ROWS_PER_BLOCK 64
#define KTILE 64
#define PAD 132   // 128 + 4 floats pad -> bank-conflict-free / 2-way only

// ---------- kernel 1: ||e_k||^2 ----------
__global__ void enorm_kernel(const float* __restrict__ embed, float* __restrict__ enorm) {
    int k = blockIdx.x * blockDim.x + threadIdx.x;
    if (k < KCODES) {
        const float4* row = (const float4*)(embed + (size_t)k * DIM);
        float s = 0.f;
#pragma unroll
        for (int d = 0; d < DIM / 4; ++d) {
            float4 v = row[d];
            s = fmaf(v.x, v.x, s);
            s = fmaf(v.y, v.y, s);
            s = fmaf(v.z, v.z, s);
            s = fmaf(v.w, v.w, s);
        }
        enorm[k] = s;
    }
}

// ---------- kernel 2: distance + argmax ----------
// block: 256 threads = 16 (ty, row groups) x 16 (tx, code groups)
// each thread: rows {ty, ty+16, ty+32, ty+48}, codes {tx, tx+16, tx+32, tx+48} of a 64-code tile
__global__ __launch_bounds__(256, 2)
void argmax_kernel(const float* __restrict__ x, const float* __restrict__ embed,
                   const float* __restrict__ enorm, int* __restrict__ out_idx) {
    __shared__ float xs[ROWS_PER_BLOCK][PAD];
    __shared__ float es[KTILE][PAD];
    __shared__ float red_best[ROWS_PER_BLOCK][16];
    __shared__ int   red_idx [ROWS_PER_BLOCK][16];

    const int tid = threadIdx.x;
    const int tx = tid & 15;
    const int ty = tid >> 4;
    const size_t row0 = (size_t)blockIdx.x * ROWS_PER_BLOCK;

    // stage x tile: 64 rows x 128 f32 = 2048 float4, 8 per thread (coalesced)
    {
        const float4* xg = (const float4*)(x + row0 * DIM);
#pragma unroll
        for (int i = 0; i < 8; ++i) {
            int e = tid + i * 256;
            int r = e >> 5;          // 32 float4 per row
            int c = (e & 31) * 4;
            *(float4*)&xs[r][c] = xg[e];
        }
    }

    float best[4];
    int   bidx[4];
#pragma unroll
    for (int i = 0; i < 4; ++i) { best[i] = -3.4e38f; bidx[i] = 0; }

    for (int kt = 0; kt < KCODES / KTILE; ++kt) {
        __syncthreads();
        // stage e tile: 64 codes x 128 f32
        {
            const float4* eg = (const float4*)(embed + (size_t)kt * KTILE * DIM);
#pragma unroll
            for (int i = 0; i < 8; ++i) {
                int e = tid + i * 256;
                int r = e >> 5;
                int c = (e & 31) * 4;
                *(float4*)&es[r][c] = eg[e];
            }
        }
        __syncthreads();

        float acc[4][4];
#pragma unroll
        for (int i = 0; i < 4; ++i)
#pragma unroll
            for (int j = 0; j < 4; ++j) acc[i][j] = 0.f;

#pragma unroll 4
        for (int d = 0; d < DIM; d += 4) {
            float4 xa[4], eb[4];
#pragma unroll
            for (int i = 0; i < 4; ++i) xa[i] = *(const float4*)&xs[ty + 16 * i][d];
#pragma unroll
            for (int j = 0; j < 4; ++j) eb[j] = *(const float4*)&es[tx + 16 * j][d];
#pragma unroll
            for (int i = 0; i < 4; ++i)
#pragma unroll
                for (int j = 0; j < 4; ++j) {
                    acc[i][j] = fmaf(xa[i].x, eb[j].x, acc[i][j]);
                    acc[i][j] = fmaf(xa[i].y, eb[j].y, acc[i][j]);
                    acc[i][j] = fmaf(xa[i].z, eb[j].z, acc[i][j]);
                    acc[i][j] = fmaf(xa[i].w, eb[j].w, acc[i][j]);
                }
        }

        // score s = 2*dot - ||e||^2 (row-constant -||x||^2 dropped; argmax invariant)
#pragma unroll
        for (int j = 0; j < 4; ++j) {           // j ascending -> code ascending within thread
            int c = kt * KTILE + tx + 16 * j;
            float en = enorm[c];
#pragma unroll
            for (int i = 0; i < 4; ++i) {
                float s = fmaf(2.f, acc[i][j], -en);
                if (s > best[i]) { best[i] = s; bidx[i] = c; }
            }
        }
    }

    // cross-tx reduction per row
#pragma unroll
    for (int i = 0; i < 4; ++i) {
        red_best[ty + 16 * i][tx] = best[i];
        red_idx [ty + 16 * i][tx] = bidx[i];
    }
    __syncthreads();
    if (tid < ROWS_PER_BLOCK) {
        float b = -3.4e38f;
        int bi = 0x7fffffff;
#pragma unroll
        for (int t = 0; t < 16; ++t) {
            float s = red_best[tid][t];
            int   c = red_idx [tid][t];
            if (s > b || (s == b && c < bi)) { b = s; bi = c; }
        }
        out_idx[row0 + tid] = bi;
    }
}

// ---------- kernel 3: gather + index write ----------
__global__ void gather_kernel(const float* __restrict__ embed, const int* __restrict__ idx,
                              float* __restrict__ outq, float* __restrict__ outi, int n_rows) {
    int t = blockIdx.x * blockDim.x + threadIdx.x;   // over n_rows*32 float4
    if (t < n_rows * 32) {
        int row = t >> 5;
        int d4  = t & 31;
        int id  = idx[row];
        float4 v = ((const float4*)(embed + (size_t)id * DIM))[d4];
        ((float4*)outq)[t] = v;
        if (t < n_rows) outi[t] = (float)idx[t];
    }
}

extern "C" void kernel_launch(void* const* d_in, const int* in_sizes, int n_in,
                              void* d_out, int out_size, void* d_ws, size_t ws_size,
                              hipStream_t stream) {
    const float* x     = (const float*)d_in[0];
    const float* embed = (const float*)d_in[1];
    const int x_elems  = in_sizes[0];          // 12,288,000
    const int n_rows   = x_elems / DIM;        // 96,000

    float* enorm = (float*)d_ws;                         // 1024 floats
    int*   idxb  = (int*)((char*)d_ws + 4096);           // 96,000 ints

    float* outq = (float*)d_out;                         // [n_rows*DIM]
    float* outi = (float*)d_out + (size_t)x_elems;       // [n_rows] as float

    enorm_kernel<<<(KCODES + 255) / 256, 256, 0, stream>>>(embed, enorm);
    argmax_kernel<<<n_rows / ROWS_PER_BLOCK, 256, 0, stream>>>(x, embed, enorm, idxb);
    gather_kernel<<<(n_rows * 32 + 255) / 256, 256, 0, stream>>>(embed, idxb, outq, outi, n_rows);
}

// Round 2
// 287.334 us; speedup vs baseline: 1.6643x; 1.6643x over previous
//
#include <hip/hip_runtime.h>
#include <hip/hip_bf16.h>

#define DIM 128
#define KCODES 1024
#define BROWS 128        // rows per block
#define WROWS 32         // rows per wave
#define NCHUNK 64        // codes per LDS chunk
#define ESTRIDE 136      // shorts per LDS row: 128 + 8 pad -> conflict-free b128
#define TAU 2e-3f

typedef __attribute__((ext_vector_type(8))) short bf16x8;
typedef __attribute__((ext_vector_type(4))) float f32x4;

__device__ __forceinline__ unsigned short f2bf(float x, float* back) {
    __hip_bfloat16 h = __float2bfloat16(x);   // RNE
    *back = __bfloat162float(h);
    union { __hip_bfloat16 hh; unsigned short u; } cv; cv.hh = h;
    return cv.u;
}

// ---------- prep: E -> bf16 hi/lo split + ||e||^2 ----------
__global__ void prep_kernel(const float* __restrict__ embed, unsigned short* __restrict__ Ehi,
                            unsigned short* __restrict__ Elo, float* __restrict__ enorm) {
    int k = blockIdx.x * blockDim.x + threadIdx.x;
    if (k >= KCODES) return;
    const float4* row = (const float4*)(embed + (size_t)k * DIM);
    float s = 0.f;
#pragma unroll
    for (int i = 0; i < DIM / 4; ++i) {
        float4 v = row[i];
        float bk, dd;
        ushort4 hv, lv;
        hv.x = f2bf(v.x, &bk); lv.x = f2bf(v.x - bk, &dd);
        hv.y = f2bf(v.y, &bk); lv.y = f2bf(v.y - bk, &dd);
        hv.z = f2bf(v.z, &bk); lv.z = f2bf(v.z - bk, &dd);
        hv.w = f2bf(v.w, &bk); lv.w = f2bf(v.w - bk, &dd);
        ((ushort4*)(Ehi + (size_t)k * DIM))[i] = hv;
        ((ushort4*)(Elo + (size_t)k * DIM))[i] = lv;
        s = fmaf(v.x, v.x, s); s = fmaf(v.y, v.y, s);
        s = fmaf(v.z, v.z, s); s = fmaf(v.w, v.w, s);
    }
    enorm[k] = s;
}

// ---------- main: split-bf16 MFMA argmax + top-2 refine guard + fused gather ----------
__global__ __launch_bounds__(256, 3)
void argmax_mfma_kernel(const float* __restrict__ x, const float* __restrict__ embed,
                        const unsigned short* __restrict__ Ehi, const unsigned short* __restrict__ Elo,
                        const float* __restrict__ enorm,
                        float* __restrict__ outq, float* __restrict__ outi) {
    __shared__ __align__(16) short esh[NCHUNK * ESTRIDE];
    __shared__ __align__(16) short esl[NCHUNK * ESTRIDE];
    __shared__ int idx_l[BROWS];
    __shared__ int flist[BROWS];
    __shared__ int fcnt;

    const int tid = threadIdx.x;
    const int w = tid >> 6;          // wave id 0..3
    const int lane = tid & 63;
    const int n = lane & 15;         // col (code) class / A row
    const int q = lane >> 4;         // quad -> k segment (A/B), row group (C)
    const size_t row0 = (size_t)blockIdx.x * BROWS;

    if (tid == 0) fcnt = 0;

    // A fragments: this wave's 32 rows, bf16 hi/lo, kept in registers for the whole N loop.
    // layout: A[m=lane&15][k=quad*8+j], k = ks*32 + q*8 + j
    bf16x8 ahi[2][4], alo[2][4];
#pragma unroll
    for (int s = 0; s < 2; ++s) {
#pragma unroll
        for (int ks = 0; ks < 4; ++ks) {
            const float* xp = x + (row0 + w * WROWS + s * 16 + n) * DIM + ks * 32 + q * 8;
            float4 a0 = *(const float4*)xp;
            float4 a1 = *(const float4*)(xp + 4);
            float f[8] = {a0.x, a0.y, a0.z, a0.w, a1.x, a1.y, a1.z, a1.w};
            bf16x8 h8, l8;
#pragma unroll
            for (int j = 0; j < 8; ++j) {
                float bk, dd;
                h8[j] = (short)f2bf(f[j], &bk);
                l8[j] = (short)f2bf(f[j] - bk, &dd);
            }
            ahi[s][ks] = h8; alo[s][ks] = l8;
        }
    }

    float best[2][4], sec[2][4];
    int bidx[2][4];
#pragma unroll
    for (int s = 0; s < 2; ++s)
#pragma unroll
        for (int r = 0; r < 4; ++r) { best[s][r] = -3.4e38f; sec[s][r] = -3.4e38f; bidx[s][r] = 0; }

    for (int kt = 0; kt < KCODES / NCHUNK; ++kt) {
        const int c0 = kt * NCHUNK;
        __syncthreads();
        // stage E chunk (hi+lo) into LDS; coalesced global reads, 2-way-max LDS writes
#pragma unroll
        for (int i = 0; i < 4; ++i) {
            int e = tid + i * 256;
            int r = e >> 4, c = e & 15;
            *(bf16x8*)&esh[r * ESTRIDE + c * 8] = *(const bf16x8*)&Ehi[(size_t)(c0 + r) * DIM + c * 8];
            *(bf16x8*)&esl[r * ESTRIDE + c * 8] = *(const bf16x8*)&Elo[(size_t)(c0 + r) * DIM + c * 8];
        }
        __syncthreads();

#pragma unroll
        for (int ns = 0; ns < 4; ++ns) {
            f32x4 acc0 = {0.f, 0.f, 0.f, 0.f};
            f32x4 acc1 = {0.f, 0.f, 0.f, 0.f};
#pragma unroll
            for (int ks = 0; ks < 4; ++ks) {
                bf16x8 bh = *(bf16x8*)&esh[(ns * 16 + n) * ESTRIDE + ks * 32 + q * 8];
                bf16x8 bl = *(bf16x8*)&esl[(ns * 16 + n) * ESTRIDE + ks * 32 + q * 8];
                acc0 = __builtin_amdgcn_mfma_f32_16x16x32_bf16(ahi[0][ks], bh, acc0, 0, 0, 0);
                acc1 = __builtin_amdgcn_mfma_f32_16x16x32_bf16(ahi[1][ks], bh, acc1, 0, 0, 0);
                acc0 = __builtin_amdgcn_mfma_f32_16x16x32_bf16(alo[0][ks], bh, acc0, 0, 0, 0);
                acc1 = __builtin_amdgcn_mfma_f32_16x16x32_bf16(alo[1][ks], bh, acc1, 0, 0, 0);
                acc0 = __builtin_amdgcn_mfma_f32_16x16x32_bf16(ahi[0][ks], bl, acc0, 0, 0, 0);
                acc1 = __builtin_amdgcn_mfma_f32_16x16x32_bf16(ahi[1][ks], bl, acc1, 0, 0, 0);
            }
            int code = c0 + ns * 16 + n;
            float en = enorm[code];
#pragma unroll
            for (int rg = 0; rg < 4; ++rg) {
                float sc0 = fmaf(2.f, acc0[rg], -en);
                if (sc0 > best[0][rg]) { sec[0][rg] = best[0][rg]; best[0][rg] = sc0; bidx[0][rg] = code; }
                else if (sc0 > sec[0][rg]) sec[0][rg] = sc0;
                float sc1 = fmaf(2.f, acc1[rg], -en);
                if (sc1 > best[1][rg]) { sec[1][rg] = best[1][rg]; best[1][rg] = sc1; bidx[1][rg] = code; }
                else if (sc1 > sec[1][rg]) sec[1][rg] = sc1;
            }
        }
    }

    // reduce top-2 across the 16 col-classes (lanes differing in bits 0..3)
#pragma unroll
    for (int mask = 1; mask < 16; mask <<= 1) {
#pragma unroll
        for (int s = 0; s < 2; ++s)
#pragma unroll
            for (int rg = 0; rg < 4; ++rg) {
                float ob = __shfl_xor(best[s][rg], mask);
                float os = __shfl_xor(sec[s][rg], mask);
                int   oi = __shfl_xor(bidx[s][rg], mask);
                if (ob > best[s][rg] || (ob == best[s][rg] && oi < bidx[s][rg])) {
                    sec[s][rg] = fmaxf(best[s][rg], os);
                    best[s][rg] = ob; bidx[s][rg] = oi;
                } else {
                    sec[s][rg] = fmaxf(sec[s][rg], ob);
                }
            }
    }
    if (n == 0) {
#pragma unroll
        for (int s = 0; s < 2; ++s)
#pragma unroll
            for (int rg = 0; rg < 4; ++rg) {
                int r = w * WROWS + s * 16 + q * 4 + rg;
                idx_l[r] = bidx[s][rg];
                if (best[s][rg] - sec[s][rg] < TAU) {
                    int p = atomicAdd(&fcnt, 1);
                    flist[p] = r;
                }
            }
    }
    __syncthreads();

    // exact fp32 refine for near-tie rows (same arithmetic as the round-1 all-fp32 kernel)
    int nf = fcnt;
    for (int f = w; f < nf; f += 4) {
        int r = flist[f];
        const float4* xg4 = (const float4*)(x + (row0 + r) * DIM);
        float b = -3.4e38f; int bi = 0;
        for (int c = lane * 16; c < lane * 16 + 16; ++c) {
            const float4* eg4 = (const float4*)(embed + (size_t)c * DIM);
            float s = 0.f;
#pragma unroll 8
            for (int d = 0; d < DIM / 4; ++d) {
                float4 xv = xg4[d], ev = eg4[d];
                s = fmaf(xv.x, ev.x, s); s = fmaf(xv.y, ev.y, s);
                s = fmaf(xv.z, ev.z, s); s = fmaf(xv.w, ev.w, s);
            }
            float sc = fmaf(2.f, s, -enorm[c]);
            if (sc > b) { b = sc; bi = c; }
        }
#pragma unroll
        for (int mask = 1; mask < 64; mask <<= 1) {
            float ob = __shfl_xor(b, mask);
            int   oi = __shfl_xor(bi, mask);
            if (ob > b || (ob == b && oi < bi)) { b = ob; bi = oi; }
        }
        if (lane == 0) idx_l[r] = bi;
    }
    __syncthreads();

    // fused gather (embed is L2-resident) + float index write
    const float4* e4 = (const float4*)embed;
    float4* oq4 = (float4*)outq + row0 * (DIM / 4);
#pragma unroll
    for (int i = 0; i < 16; ++i) {
        int g = tid + i * 256;
        int r = g >> 5, d4 = g & 31;
        int id = idx_l[r];
        oq4[g] = e4[(size_t)id * (DIM / 4) + d4];
    }
    if (tid < BROWS) outi[row0 + tid] = (float)idx_l[tid];
}

extern "C" void kernel_launch(void* const* d_in, const int* in_sizes, int n_in,
                              void* d_out, int out_size, void* d_ws, size_t ws_size,
                              hipStream_t stream) {
    const float* x     = (const float*)d_in[0];
    const float* embed = (const float*)d_in[1];
    const int x_elems  = in_sizes[0];          // 12,288,000
    const int n_rows   = x_elems / DIM;        // 96,000

    float*          enorm = (float*)d_ws;                                   // 4 KB
    unsigned short* Ehi   = (unsigned short*)((char*)d_ws + 4096);          // 256 KB
    unsigned short* Elo   = Ehi + (size_t)KCODES * DIM;                     // 256 KB

    float* outq = (float*)d_out;
    float* outi = (float*)d_out + (size_t)x_elems;

    prep_kernel<<<KCODES / 128, 128, 0, stream>>>(embed, Ehi, Elo, enorm);
    argmax_mfma_kernel<<<n_rows / BROWS, 256, 0, stream>>>(x, embed, Ehi, Elo, enorm, outq, outi);
}

// Round 3
// 284.133 us; speedup vs baseline: 1.6830x; 1.0113x over previous
//
#include <hip/hip_runtime.h>
#include <hip/hip_bf16.h>

#define DIM 128
#define KCODES 1024
#define BROWS 128        // rows per block (4 waves x 32 rows)
#define NCHUNK 64        // codes per LDS chunk
#define TAU 2e-3f

typedef __attribute__((ext_vector_type(8))) short bf16x8;
typedef __attribute__((ext_vector_type(4))) float f32x4;

__device__ __forceinline__ unsigned short f2bf(float x, float* back) {
    __hip_bfloat16 h = __float2bfloat16(x);   // RNE
    *back = __bfloat162float(h);
    union { __hip_bfloat16 hh; unsigned short u; } cv; cv.hh = h;
    return cv.u;
}

// ---------- prep A: ||e_k||^2 ----------
__global__ void enorm_kernel(const float* __restrict__ embed, float* __restrict__ enorm) {
    int k = blockIdx.x * blockDim.x + threadIdx.x;
    if (k < KCODES) {
        const float4* row = (const float4*)(embed + (size_t)k * DIM);
        float s = 0.f;
#pragma unroll
        for (int d = 0; d < DIM / 4; ++d) {
            float4 v = row[d];
            s = fmaf(v.x, v.x, s); s = fmaf(v.y, v.y, s);
            s = fmaf(v.z, v.z, s); s = fmaf(v.w, v.w, s);
        }
        enorm[k] = s;
    }
}

// ---------- prep B: E -> bf16 hi/lo, XOR-swizzled segment layout ----------
// Segment = 8 shorts (16 B). Row r's logical segment s is stored at s ^ (r & 15).
// Staging then copies lane-linearly (conflict-free LDS writes); the MFMA B-read
// deswizzles with (ks*4+q)^n, giving 2-way-max bank aliasing (free per m136).
__global__ void pack_kernel(const float* __restrict__ embed, unsigned short* __restrict__ Ehi,
                            unsigned short* __restrict__ Elo) {
    int t = blockIdx.x * blockDim.x + threadIdx.x;   // 0 .. KCODES*16-1
    int k = t >> 4;          // code row
    int s = t & 15;          // logical 16B segment
    int r = k & 63;          // row within chunk
    const float* src = embed + (size_t)k * DIM + s * 8;
    float4 a0 = *(const float4*)src;
    float4 a1 = *(const float4*)(src + 4);
    float f[8] = {a0.x, a0.y, a0.z, a0.w, a1.x, a1.y, a1.z, a1.w};
    bf16x8 h8, l8;
#pragma unroll
    for (int j = 0; j < 8; ++j) {
        float bk, dd;
        h8[j] = (short)f2bf(f[j], &bk);
        l8[j] = (short)f2bf(f[j] - bk, &dd);
    }
    size_t dst = (size_t)k * DIM + ((s ^ (r & 15)) * 8);
    *(bf16x8*)&Ehi[dst] = h8;
    *(bf16x8*)&Elo[dst] = l8;
}

// ---------- main: split-bf16 MFMA argmax + top-2 refine guard + fused gather ----------
__global__ __launch_bounds__(256, 3)
void argmax_mfma_kernel(const float* __restrict__ x, const float* __restrict__ embed,
                        const unsigned short* __restrict__ Ehi, const unsigned short* __restrict__ Elo,
                        const float* __restrict__ enorm,
                        float* __restrict__ outq, float* __restrict__ outi) {
    __shared__ __align__(16) short esh[NCHUNK * DIM];   // 16 KB, swizzled
    __shared__ __align__(16) short esl[NCHUNK * DIM];   // 16 KB, swizzled
    __shared__ int idx_l[BROWS];
    __shared__ int flist[BROWS];
    __shared__ int fcnt;

    const int tid = threadIdx.x;
    const int w = tid >> 6;          // wave id 0..3
    const int lane = tid & 63;
    const int n = lane & 15;         // col (code) class / A row
    const int q = lane >> 4;         // quad -> k segment (A/B), row group (C)
    const size_t row0 = (size_t)blockIdx.x * BROWS;

    if (tid == 0) fcnt = 0;

    // A fragments: wave's 32 rows, bf16 hi/lo, in registers for the whole loop.
    // layout: A[m=lane&15][k=quad*8+j], k = ks*32 + q*8 + j  (verified round 2)
    bf16x8 ahi[2][4], alo[2][4];
#pragma unroll
    for (int s = 0; s < 2; ++s) {
#pragma unroll
        for (int ks = 0; ks < 4; ++ks) {
            const float* xp = x + (row0 + w * 32 + s * 16 + n) * DIM + ks * 32 + q * 8;
            float4 a0 = *(const float4*)xp;
            float4 a1 = *(const float4*)(xp + 4);
            float f[8] = {a0.x, a0.y, a0.z, a0.w, a1.x, a1.y, a1.z, a1.w};
            bf16x8 h8, l8;
#pragma unroll
            for (int j = 0; j < 8; ++j) {
                float bk, dd;
                h8[j] = (short)f2bf(f[j], &bk);
                l8[j] = (short)f2bf(f[j] - bk, &dd);
            }
            ahi[s][ks] = h8; alo[s][ks] = l8;
        }
    }

    float best[2][4], sec[2][4];
    int bidx[2][4];
#pragma unroll
    for (int s = 0; s < 2; ++s)
#pragma unroll
        for (int r = 0; r < 4; ++r) { best[s][r] = -3.4e38f; sec[s][r] = -3.4e38f; bidx[s][r] = 0; }

    // prefetch chunk 0 into registers (8 x b128 per thread)
    bf16x8 pf[8];
#pragma unroll
    for (int j = 0; j < 4; ++j) {
        pf[j]     = *(const bf16x8*)&Ehi[(size_t)(tid + j * 256) * 8];
        pf[4 + j] = *(const bf16x8*)&Elo[(size_t)(tid + j * 256) * 8];
    }

    for (int kt = 0; kt < KCODES / NCHUNK; ++kt) {
        __syncthreads();                       // previous chunk's LDS reads done
        // lane-linear store of prefetched chunk (conflict-free: 2-way max)
#pragma unroll
        for (int j = 0; j < 4; ++j) {
            *(bf16x8*)&esh[(tid + j * 256) * 8] = pf[j];
            *(bf16x8*)&esl[(tid + j * 256) * 8] = pf[4 + j];
        }
        // issue next chunk's global loads; consumed at next loop top (latency hidden)
        if (kt + 1 < KCODES / NCHUNK) {
            const size_t nb = (size_t)(kt + 1) * NCHUNK * DIM;
#pragma unroll
            for (int j = 0; j < 4; ++j) {
                pf[j]     = *(const bf16x8*)&Ehi[nb + (size_t)(tid + j * 256) * 8];
                pf[4 + j] = *(const bf16x8*)&Elo[nb + (size_t)(tid + j * 256) * 8];
            }
        }
        __syncthreads();                       // staged chunk visible

        const int c0 = kt * NCHUNK;
#pragma unroll
        for (int ns = 0; ns < 4; ++ns) {
            f32x4 acc0 = {0.f, 0.f, 0.f, 0.f};
            f32x4 acc1 = {0.f, 0.f, 0.f, 0.f};
#pragma unroll
            for (int ks = 0; ks < 4; ++ks) {
                // deswizzled read: logical seg ks*4+q of row ns*16+n
                int off = (ns * 16 + n) * DIM + (((ks * 4 + q) ^ n) * 8);
                bf16x8 bh = *(bf16x8*)&esh[off];
                bf16x8 bl = *(bf16x8*)&esl[off];
                acc0 = __builtin_amdgcn_mfma_f32_16x16x32_bf16(ahi[0][ks], bh, acc0, 0, 0, 0);
                acc1 = __builtin_amdgcn_mfma_f32_16x16x32_bf16(ahi[1][ks], bh, acc1, 0, 0, 0);
                acc0 = __builtin_amdgcn_mfma_f32_16x16x32_bf16(alo[0][ks], bh, acc0, 0, 0, 0);
                acc1 = __builtin_amdgcn_mfma_f32_16x16x32_bf16(alo[1][ks], bh, acc1, 0, 0, 0);
                acc0 = __builtin_amdgcn_mfma_f32_16x16x32_bf16(ahi[0][ks], bl, acc0, 0, 0, 0);
                acc1 = __builtin_amdgcn_mfma_f32_16x16x32_bf16(ahi[1][ks], bl, acc1, 0, 0, 0);
            }
            int code = c0 + ns * 16 + n;
            float en = enorm[code];
#pragma unroll
            for (int rg = 0; rg < 4; ++rg) {
                float sc0 = fmaf(2.f, acc0[rg], -en);
                if (sc0 > best[0][rg]) { sec[0][rg] = best[0][rg]; best[0][rg] = sc0; bidx[0][rg] = code; }
                else if (sc0 > sec[0][rg]) sec[0][rg] = sc0;
                float sc1 = fmaf(2.f, acc1[rg], -en);
                if (sc1 > best[1][rg]) { sec[1][rg] = best[1][rg]; best[1][rg] = sc1; bidx[1][rg] = code; }
                else if (sc1 > sec[1][rg]) sec[1][rg] = sc1;
            }
        }
    }

    // reduce top-2 across the 16 col-classes (lanes differing in bits 0..3)
#pragma unroll
    for (int mask = 1; mask < 16; mask <<= 1) {
#pragma unroll
        for (int s = 0; s < 2; ++s)
#pragma unroll
            for (int rg = 0; rg < 4; ++rg) {
                float ob = __shfl_xor(best[s][rg], mask);
                float os = __shfl_xor(sec[s][rg], mask);
                int   oi = __shfl_xor(bidx[s][rg], mask);
                if (ob > best[s][rg] || (ob == best[s][rg] && oi < bidx[s][rg])) {
                    sec[s][rg] = fmaxf(best[s][rg], os);
                    best[s][rg] = ob; bidx[s][rg] = oi;
                } else {
                    sec[s][rg] = fmaxf(sec[s][rg], ob);
                }
            }
    }
    if (n == 0) {
#pragma unroll
        for (int s = 0; s < 2; ++s)
#pragma unroll
            for (int rg = 0; rg < 4; ++rg) {
                int r = w * 32 + s * 16 + q * 4 + rg;
                idx_l[r] = bidx[s][rg];
                if (best[s][rg] - sec[s][rg] < TAU) {
                    int p = atomicAdd(&fcnt, 1);
                    flist[p] = r;
                }
            }
    }
    __syncthreads();

    // exact fp32 refine for near-tie rows (same arithmetic as the round-1 all-fp32 kernel)
    int nf = fcnt;
    for (int f = w; f < nf; f += 4) {
        int r = flist[f];
        const float4* xg4 = (const float4*)(x + (row0 + r) * DIM);
        float b = -3.4e38f; int bi = 0;
        for (int c = lane * 16; c < lane * 16 + 16; ++c) {
            const float4* eg4 = (const float4*)(embed + (size_t)c * DIM);
            float s = 0.f;
#pragma unroll 8
            for (int d = 0; d < DIM / 4; ++d) {
                float4 xv = xg4[d], ev = eg4[d];
                s = fmaf(xv.x, ev.x, s); s = fmaf(xv.y, ev.y, s);
                s = fmaf(xv.z, ev.z, s); s = fmaf(xv.w, ev.w, s);
            }
            float sc = fmaf(2.f, s, -enorm[c]);
            if (sc > b) { b = sc; bi = c; }
        }
#pragma unroll
        for (int mask = 1; mask < 64; mask <<= 1) {
            float ob = __shfl_xor(b, mask);
            int   oi = __shfl_xor(bi, mask);
            if (ob > b || (ob == b && oi < bi)) { b = ob; bi = oi; }
        }
        if (lane == 0) idx_l[r] = bi;
    }
    __syncthreads();

    // fused gather (embed is L2-resident) + float index write
    const float4* e4 = (const float4*)embed;
    float4* oq4 = (float4*)outq + row0 * (DIM / 4);
#pragma unroll
    for (int i = 0; i < 16; ++i) {
        int g = tid + i * 256;
        int r = g >> 5, d4 = g & 31;
        int id = idx_l[r];
        oq4[g] = e4[(size_t)id * (DIM / 4) + d4];
    }
    if (tid < BROWS) outi[row0 + tid] = (float)idx_l[tid];
}

extern "C" void kernel_launch(void* const* d_in, const int* in_sizes, int n_in,
                              void* d_out, int out_size, void* d_ws, size_t ws_size,
                              hipStream_t stream) {
    const float* x     = (const float*)d_in[0];
    const float* embed = (const float*)d_in[1];
    const int x_elems  = in_sizes[0];          // 12,288,000
    const int n_rows   = x_elems / DIM;        // 96,000

    float*          enorm = (float*)d_ws;                                   // 4 KB
    unsigned short* Ehi   = (unsigned short*)((char*)d_ws + 4096);          // 256 KB
    unsigned short* Elo   = Ehi + (size_t)KCODES * DIM;                     // 256 KB

    float* outq = (float*)d_out;
    float* outi = (float*)d_out + (size_t)x_elems;

    enorm_kernel<<<KCODES / 256, 256, 0, stream>>>(embed, enorm);
    pack_kernel<<<KCODES * 16 / 256, 256, 0, stream>>>(embed, Ehi, Elo);
    argmax_mfma_kernel<<<n_rows / BROWS, 256, 0, stream>>>(x, embed, Ehi, Elo, enorm, outq, outi);
}